// Round 10
// baseline (1219.501 us; speedup 1.0000x reference)
//
#include <hip/hip_runtime.h>
#include <cstddef>
#include <cstdint>

// Problem constants: EMBED=1024, NUM_HEADS=16, GQA=4, KV_HEADS=4,
// HEAD_DIM=64, KV_EMBED=256, EPS=1e-3, B=2, T=1024.
#define TSEQ 1024

typedef __attribute__((ext_vector_type(8))) short short8;   // 8 bf16 = 4 VGPRs
typedef __attribute__((ext_vector_type(4))) float floatx4;  // MFMA acc

// Workspace layout (floats):
//  XQ : 2048 x 1024  (2M)   (also reused as never-written sink for check_k)
//  XK : 2048 x 256   (0.5M)
//  XVt: 2 x 256 x 1024 (0.5M)  -- V-projection TRANSPOSED: [b][h*64+c][j]
//  XO : 2048 x 1024  (2M)   (probe dummy target first, then pv overwrites)
//  P  : 32 x 1024x1024 (33.55M) -- probs, overwritten in place by phi
static constexpr size_t OFF_XQ  = 0;
static constexpr size_t OFF_XK  = (size_t)2 * 1024 * 1024;
static constexpr size_t OFF_XVT = OFF_XK + (size_t)512 * 1024;
static constexpr size_t OFF_XO  = OFF_XVT + (size_t)512 * 1024;
static constexpr size_t OFF_P   = OFF_XO + (size_t)2 * 1024 * 1024;

// ---------------------------------------------------------------------------
// fp32 -> bf16 hi/lo split (RNE). x ≈ hi + lo with residual ~2^-17 |x|.
// ---------------------------------------------------------------------------
__device__ __forceinline__ void cvt_hi_lo(float x, unsigned short& hi,
                                          unsigned short& lo) {
  unsigned u = __float_as_uint(x);
  unsigned rh = (u + 0x7FFFu + ((u >> 16) & 1u)) & 0xFFFF0000u;
  hi = (unsigned short)(rh >> 16);
  float xl = x - __uint_as_float(rh);
  unsigned ul = __float_as_uint(xl);
  unsigned rl = ul + 0x7FFFu + ((ul >> 16) & 1u);
  lo = (unsigned short)(rl >> 16);
}

// ---------------------------------------------------------------------------
// Unified NT GEMM core, MFMA bf16x3 (R5-proven, do not touch).
// ---------------------------------------------------------------------------
template <int EPI>
__device__ __forceinline__ void mfma_nt_core(
    const float* __restrict__ A, int lda,
    const float* __restrict__ B, int ldb,
    float* __restrict__ C, int ldc, int K,
    const float* __restrict__ bias)
{
  __shared__ __align__(16) unsigned short Ah[64][40];
  __shared__ __align__(16) unsigned short Al[64][40];
  __shared__ __align__(16) unsigned short Bh[64][40];
  __shared__ __align__(16) unsigned short Bl[64][40];

  const int bm = blockIdx.y << 6;
  const int bn = blockIdx.x << 6;
  const int tid  = threadIdx.x;
  const int lane = tid & 63;
  const int wave = tid >> 6;
  const int m16  = lane & 15;
  const int quad = lane >> 4;

  const int srow = tid >> 2;
  const int skq  = (tid & 3) << 3;

  floatx4 acc[4];
#pragma unroll
  for (int c = 0; c < 4; ++c) acc[c] = (floatx4){0.f, 0.f, 0.f, 0.f};

  for (int k0 = 0; k0 < K; k0 += 32) {
    {
      const float* ap = A + (size_t)(bm + srow) * lda + (k0 + skq);
      const float* bp = B + (size_t)(bn + srow) * ldb + (k0 + skq);
      float av[8] __attribute__((aligned(16)));
      float bv[8] __attribute__((aligned(16)));
      *(float4*)&av[0] = *(const float4*)(ap);
      *(float4*)&av[4] = *(const float4*)(ap + 4);
      *(float4*)&bv[0] = *(const float4*)(bp);
      *(float4*)&bv[4] = *(const float4*)(bp + 4);
      short8 vah, valo, vbh, vblo;
#pragma unroll
      for (int e = 0; e < 8; ++e) {
        unsigned short h, l;
        cvt_hi_lo(av[e], h, l);
        vah[e] = (short)h; valo[e] = (short)l;
        cvt_hi_lo(bv[e], h, l);
        vbh[e] = (short)h; vblo[e] = (short)l;
      }
      *(short8*)&Ah[srow][skq] = vah;
      *(short8*)&Al[srow][skq] = valo;
      *(short8*)&Bh[srow][skq] = vbh;
      *(short8*)&Bl[srow][skq] = vblo;
    }
    __syncthreads();

    const int arow = (wave << 4) + m16;
    const short8 a_h = *(const short8*)&Ah[arow][quad << 3];
    const short8 a_l = *(const short8*)&Al[arow][quad << 3];
#pragma unroll
    for (int c = 0; c < 4; ++c) {
      const int brow = (c << 4) + m16;
      const short8 b_h = *(const short8*)&Bh[brow][quad << 3];
      const short8 b_l = *(const short8*)&Bl[brow][quad << 3];
      acc[c] = __builtin_amdgcn_mfma_f32_16x16x32_bf16(a_h, b_h, acc[c], 0, 0, 0);
      acc[c] = __builtin_amdgcn_mfma_f32_16x16x32_bf16(a_h, b_l, acc[c], 0, 0, 0);
      acc[c] = __builtin_amdgcn_mfma_f32_16x16x32_bf16(a_l, b_h, acc[c], 0, 0, 0);
    }
    __syncthreads();
  }

#pragma unroll
  for (int c = 0; c < 4; ++c) {
#pragma unroll
    for (int r = 0; r < 4; ++r) {
      const int row = (wave << 4) + (quad << 2) + r;
      const int col = (c << 4) + m16;
      float v = acc[c][r];
      if (EPI == 0) { if (bias) v += bias[bn + col]; }
      if (EPI == 1) { v += bias[bm + row]; }
      if (EPI == 2) {
        v = 1.0f / (1.0f + expf(-v));
        v = fminf(fmaxf(v, 0.001f), 0.999f);
      }
      C[(size_t)(bm + row) * ldc + (bn + col)] = v;
    }
  }
}

__global__ __launch_bounds__(256) void gemm_nt_mfma_k(
    const float* __restrict__ A, int lda, const float* __restrict__ W, int ldw,
    const float* __restrict__ bias, float* __restrict__ C, int ldc, int K)
{
  mfma_nt_core<0>(A, lda, W, ldw, C, ldc, K, bias);
}

__global__ __launch_bounds__(256) void proj_vt_k(
    const float* __restrict__ vw, const float* __restrict__ value,
    const float* __restrict__ vb, float* __restrict__ XVt)
{
  const int b = blockIdx.z;
  mfma_nt_core<1>(vw, 1024, value + ((size_t)b << 20), 1024,
                  XVt + (size_t)b * 256 * 1024, 1024, 1024, vb);
}

__global__ __launch_bounds__(256) void scores_mfma_k(
    const float* __restrict__ XQ, const float* __restrict__ XK,
    float* __restrict__ P)
{
  const int z = blockIdx.z;
  const int b = z >> 4;
  mfma_nt_core<2>(XQ + ((size_t)b << 20) + ((size_t)(z & 15) << 6), 1024,
                  XK + (size_t)b * TSEQ * 256 + ((size_t)(z & 3) << 6), 256,
                  P + ((size_t)z << 20), 1024, 64, nullptr);
}

__global__ __launch_bounds__(256) void pv_mfma_k(
    const float* __restrict__ P, const float* __restrict__ XVt,
    float* __restrict__ XO)
{
  const int z = blockIdx.z;
  const int b = z >> 4;
  mfma_nt_core<0>(P + ((size_t)z << 20), 1024,
                  XVt + (size_t)b * 256 * 1024 + (size_t)(z & 3) * 64 * 1024, 1024,
                  XO + ((size_t)b << 20) + ((size_t)(z & 15) << 6), 1024,
                  1024, nullptr);
}

// ---------------------------------------------------------------------------
// Monotonic recurrence, in place over P (probs -> phi).  [R7-PROVEN pair-scan
// — verbatim; this is the output-correct path.]
// ---------------------------------------------------------------------------
__global__ __launch_bounds__(64) void mono_rec_k(float* __restrict__ P)
{
  const int z = blockIdx.x;
  float* __restrict__ Pz = P + ((size_t)z << 20);
  const int t = threadIdx.x;
  const int col0 = t << 4;
  const int bofs = (t == 0) ? 0 : (col0 - 1);

  float b[16];

  const float p00 = Pz[0];
  {
    float4 z4 = make_float4(0.f, 0.f, 0.f, 0.f);
    float4 v0 = z4;
    if (t == 0) v0.x = 1.0f;
    *(float4*)(Pz + col0 + 0)  = v0;
    *(float4*)(Pz + col0 + 4)  = z4;
    *(float4*)(Pz + col0 + 8)  = z4;
    *(float4*)(Pz + col0 + 12) = z4;
  }
#pragma unroll
  for (int c = 0; c < 16; ++c) b[c] = 0.0f;
  if (t == 0) b[0] = p00;

  {
    float pu1[16];
#pragma unroll
    for (int q = 0; q < 4; ++q)
      *(float4*)&pu1[4 * q] = *(const float4*)(Pz + ((size_t)1 << 10) + col0 + 4 * q);

    const float pl = __shfl_up(pu1[15], 1);
    const float A0 = (t == 0) ? 0.0f : (1.0f - pl);
    float SA[16], SB[16];
    SA[0] = A0;
    SB[0] = b[0];
#pragma unroll
    for (int c = 1; c < 16; ++c) {
      const float Ac = 1.0f - pu1[c - 1];
      SA[c] = SA[c - 1] * Ac;
      SB[c] = fmaf(SB[c - 1], Ac, b[c]);
    }
    float tA = SA[15], tB = SB[15];
#pragma unroll
    for (int off = 1; off < 64; off <<= 1) {
      const float uA = __shfl_up(tA, off);
      const float uB = __shfl_up(tB, off);
      if (t >= off) { tB = fmaf(uB, tA, tB); tA = uA * tA; }
    }
    float pB = __shfl_up(tB, 1);
    if (t == 0) pB = 0.0f;
    float phin[16];
#pragma unroll
    for (int c = 0; c < 16; ++c) {
      phin[c] = fmaf(pB, SA[c], SB[c]);
      b[c] = phin[c] * pu1[c];
    }
    float* rowp = Pz + ((size_t)1 << 10) + col0;
#pragma unroll
    for (int q = 0; q < 4; ++q)
      *(float4*)(rowp + 4 * q) = *(float4*)&phin[4 * q];
  }

  float cu[16], cv[16], wu[16], wv[16];
  float cqu, cqv, wqu, wqv;

#pragma unroll
  for (int q = 0; q < 4; ++q) {
    *(float4*)&cu[4 * q] = *(const float4*)(Pz + ((size_t)2 << 10) + col0 + 4 * q);
    *(float4*)&cv[4 * q] = *(const float4*)(Pz + ((size_t)3 << 10) + col0 + 4 * q);
  }
  cqu = Pz[((size_t)2 << 10) + bofs];
  cqv = Pz[((size_t)3 << 10) + bofs];

  auto pass2 = [&](int i, float (&up)[16], float (&vp)[16],
                   const float qu, const float qv,
                   float (&pwu)[16], float (&pwv)[16],
                   float& pqu, float& pqv) {
    const size_t r2 = (size_t)((i + 2 < TSEQ) ? (i + 2) : (TSEQ - 1)) << 10;
    const size_t r3 = (size_t)((i + 3 < TSEQ) ? (i + 3) : (TSEQ - 1)) << 10;
#pragma unroll
    for (int q = 0; q < 4; ++q) {
      *(float4*)&pwu[4 * q] = *(const float4*)(Pz + r2 + col0 + 4 * q);
      *(float4*)&pwv[4 * q] = *(const float4*)(Pz + r3 + col0 + 4 * q);
    }
    pqu = Pz[r2 + bofs];
    pqv = Pz[r3 + bofs];

    const float H0 = (t == 0) ? 0.0f : (1.0f - qu);
    const float G0 = (t == 0) ? 0.0f : (1.0f - qv);

    float a = H0, d = G0;
    float bx = b[0];
    float cc = up[0] * a;
    float by = up[0] * bx;
#pragma unroll
    for (int c = 1; c < 16; ++c) {
      const float H  = 1.0f - up[c - 1];
      const float G  = 1.0f - vp[c - 1];
      const float qq = up[c];
      a  = H * a;
      bx = fmaf(H, bx, b[c]);
      cc = fmaf(G, cc, qq * a);
      by = fmaf(G, by, qq * bx);
      d  = G * d;
    }

#pragma unroll
    for (int off = 1; off < 64; off <<= 1) {
      const float ua  = __shfl_up(a, off);
      const float ucc = __shfl_up(cc, off);
      const float ud  = __shfl_up(d, off);
      const float ubx = __shfl_up(bx, off);
      const float uby = __shfl_up(by, off);
      if (t >= off) {
        const float nbx = fmaf(a, ubx, bx);
        const float nby = fmaf(cc, ubx, fmaf(d, uby, by));
        const float ncc = fmaf(cc, ua, d * ucc);
        a = a * ua;
        d = d * ud;
        bx = nbx; by = nby; cc = ncc;
      }
    }

    float Xx = __shfl_up(bx, 1);
    float Xy = __shfl_up(by, 1);
    if (t == 0) { Xx = 0.0f; Xy = 0.0f; }

    float xa[16], ya[16];
    float x = fmaf(H0, Xx, b[0]);
    float y = fmaf(G0, Xy, up[0] * x);
    xa[0] = x; ya[0] = y; b[0] = y * vp[0];
#pragma unroll
    for (int c = 1; c < 16; ++c) {
      x = fmaf(1.0f - up[c - 1], x, b[c]);
      y = fmaf(1.0f - vp[c - 1], y, up[c] * x);
      xa[c] = x; ya[c] = y; b[c] = y * vp[c];
    }
    float* rowu = Pz + ((size_t)i << 10) + col0;
    float* rowv = rowu + TSEQ;
#pragma unroll
    for (int q = 0; q < 4; ++q) {
      *(float4*)(rowu + 4 * q) = *(float4*)&xa[4 * q];
      *(float4*)(rowv + 4 * q) = *(float4*)&ya[4 * q];
    }
  };

  int i = 2;
  for (int k = 0; k < 255; ++k) {
    pass2(i, cu, cv, cqu, cqv, wu, wv, wqu, wqv);
    pass2(i + 2, wu, wv, wqu, wqv, cu, cv, cqu, cqv);
    i += 4;
  }
  pass2(1022, cu, cv, cqu, cqv, wu, wv, wqu, wqv);
}

// ---------------------------------------------------------------------------
// SKEW PROBE (instrumentation only; output never feeds the result).
// Identical compute/relay to R9's skewed pipeline, but READS P without ever
// writing it: stores go to `dummy` (XO region, later overwritten by pv), and
// only z==0 stores at all. This removes the in-place hazard entirely:
// if check_k reports a match, R9's bug was the in-place aliasing; if
// mismatch, the relay/compute logic itself is broken on HW. Its dur_us in
// rocprof is the timing verdict for the 1-shfl/slot structure.
// ---------------------------------------------------------------------------
__global__ __launch_bounds__(64) void skew_probe_k(
    const float* __restrict__ P, float* __restrict__ dummy)
{
  const int z = blockIdx.x;
  const float* __restrict__ Pz = P + ((size_t)z << 20);
  const int t = threadIdx.x;
  const int col0 = t << 4;
  const bool st = (z == 0);

  float b[16];
  float bf0[16], bf1[16], bf2[16], bf3[16];
  float cout = 0.0f;

  const float p00 = Pz[0];
  if (st) {
    float4 z4 = make_float4(0.f, 0.f, 0.f, 0.f);
    float4 v0 = z4;
    if (t == 0) v0.x = 1.0f;
    *(float4*)(dummy + col0 + 0)  = v0;
    *(float4*)(dummy + col0 + 4)  = z4;
    *(float4*)(dummy + col0 + 8)  = z4;
    *(float4*)(dummy + col0 + 12) = z4;
  }
#pragma unroll
  for (int c = 0; c < 16; ++c) b[c] = 0.0f;
  if (t == 0) b[0] = p00;

  auto ldrow = [&](int r, float (&dst)[16]) {
    r = min(max(r, 1), TSEQ - 1);
    const float* p = Pz + ((size_t)r << 10) + col0;
    float tmp[16];
#pragma unroll
    for (int q = 0; q < 4; ++q)
      *(float4*)&tmp[4 * q] = *(const float4*)(p + 4 * q);
#pragma unroll
    for (int c = 0; c < 16; ++c) dst[c] = 1.0f - tmp[c];
  };

  ldrow(1 - t, bf1);
  ldrow(2 - t, bf2);
  ldrow(3 - t, bf3);

  auto body = [&](int s, const float (&pa)[16], float (&pl)[16]) {
    const int i = s - t;
    float cin = __shfl_up(cout, 1);
    if (t == 0) cin = 0.0f;
    ldrow(s + 3 - t, pl);
    float phi[16];
    float x = cin + b[0];
    phi[0] = x;
#pragma unroll
    for (int c = 1; c < 16; ++c) {
      x = fmaf(pa[c - 1], x, b[c]);
      phi[c] = x;
    }
    cout = pa[15] * x;
    if (i < 1 || i >= TSEQ) cout = 0.0f;
    if (i >= 1 && i < TSEQ) {
#pragma unroll
      for (int c = 0; c < 16; ++c) b[c] = fmaf(-pa[c], phi[c], phi[c]);
      if (st) {
        float* rowp = dummy + ((size_t)i << 10) + col0;
#pragma unroll
        for (int q = 0; q < 4; ++q)
          *(float4*)(rowp + 4 * q) = *(float4*)&phi[4 * q];
      }
    }
  };

  for (int s = 1; s <= 1085; s += 4) {
    body(s + 0, bf1, bf0);
    body(s + 1, bf2, bf1);
    body(s + 2, bf3, bf2);
    body(s + 3, bf0, bf3);
  }
}

// ---------------------------------------------------------------------------
// Duration-encoded comparator: dummy (skew phi z0) vs P z0 (pair phi).
// Match -> ~10 us. Mismatch -> spinning blocks -> 300+ us in rocprof.
// Never writes the real output; sink write is opaquely unreachable.
// ---------------------------------------------------------------------------
__global__ __launch_bounds__(256) void check_k(
    const float* __restrict__ A, const float* __restrict__ B,
    float* __restrict__ sink)
{
  const int row = blockIdx.x + 1;          // rows 1..1023
  const int j0 = threadIdx.x << 2;
  float md = 0.0f;
#pragma unroll
  for (int q = 0; q < 4; ++q) {
    const size_t idx = ((size_t)row << 10) + j0 + q;
    md = fmaxf(md, fabsf(A[idx] - B[idx]));
  }
  if (md > 1e-3f) {
    float acc = md;
    for (int k = 0; k < 40000; ++k) acc = fmaf(acc, 1.0000001f, 1e-7f);
    if (acc == 12345.678f) sink[row] = acc;   // opaque, never true
  }
}

// ---------------------------------------------------------------------------
extern "C" void kernel_launch(void* const* d_in, const int* in_sizes, int n_in,
                              void* d_out, int out_size, void* d_ws, size_t ws_size,
                              hipStream_t stream)
{
  const float* query = (const float*)d_in[0];
  const float* key   = (const float*)d_in[1];
  const float* value = (const float*)d_in[2];
  const float* ipw   = (const float*)d_in[3];   // (1536,1024)
  const float* ipb   = (const float*)d_in[4];   // (1536,)
  const float* opw   = (const float*)d_in[5];   // (1024,1024)
  const float* opb   = (const float*)d_in[6];   // (1024,)
  float* out = (float*)d_out;
  float* ws  = (float*)d_ws;

  float* XQ  = ws + OFF_XQ;
  float* XK  = ws + OFF_XK;
  float* XVt = ws + OFF_XVT;
  float* XO  = ws + OFF_XO;
  float* P   = ws + OFF_P;

  // in-projections (MFMA bf16x3)
  gemm_nt_mfma_k<<<dim3(16, 32), 256, 0, stream>>>(
      query, 1024, ipw, 1024, ipb, XQ, 1024, 1024);
  gemm_nt_mfma_k<<<dim3(4, 32), 256, 0, stream>>>(
      key, 1024, ipw + (size_t)1024 * 1024, 1024, ipb + 1024, XK, 256, 1024);
  proj_vt_k<<<dim3(16, 4, 2), 256, 0, stream>>>(
      ipw + (size_t)1280 * 1024, value, ipb + 1280, XVt);

  // scores + sigmoid + clip -> P
  scores_mfma_k<<<dim3(16, 16, 32), 256, 0, stream>>>(XQ, XK, P);

  // INSTRUMENTATION: skew probe (reads P only; z0 phi -> XO dummy)
  skew_probe_k<<<dim3(32), dim3(64), 0, stream>>>(P, XO);

  // monotonic recurrence in place (R7-proven pair-scan) — the real path
  mono_rec_k<<<dim3(32), dim3(64), 0, stream>>>(P);

  // INSTRUMENTATION: duration-encoded skew-vs-pair comparison (z0)
  check_k<<<dim3(1023), dim3(256), 0, stream>>>(XO, P, XQ);

  // phi @ V -> XO (overwrites probe dummy)
  pv_mfma_k<<<dim3(1, 16, 32), 256, 0, stream>>>(P, XVt, XO);

  // out-projection
  gemm_nt_mfma_k<<<dim3(16, 32), 256, 0, stream>>>(
      XO, 1024, opw, 1024, opb, out, 1024, 1024);
}

// Round 11
// 827.088 us; speedup vs baseline: 1.4745x; 1.4745x over previous
//
#include <hip/hip_runtime.h>
#include <cstddef>
#include <cstdint>

// Problem constants: EMBED=1024, NUM_HEADS=16, GQA=4, KV_HEADS=4,
// HEAD_DIM=64, KV_EMBED=256, EPS=1e-3, B=2, T=1024.
#define TSEQ 1024

typedef __attribute__((ext_vector_type(8))) short short8;   // 8 bf16 = 4 VGPRs
typedef __attribute__((ext_vector_type(4))) float floatx4;  // MFMA acc

// Workspace layout (floats):
//  XQ : 2048 x 1024  (2M)
//  XK : 2048 x 256   (0.5M)
//  XVt: 2 x 256 x 1024 (0.5M)  -- V-projection TRANSPOSED: [b][h*64+c][j]
//  XO : 2048 x 1024  (2M)
//  P  : 32 x 1024x1024 (33.55M) -- probs, overwritten in place by phi
static constexpr size_t OFF_XQ  = 0;
static constexpr size_t OFF_XK  = (size_t)2 * 1024 * 1024;
static constexpr size_t OFF_XVT = OFF_XK + (size_t)512 * 1024;
static constexpr size_t OFF_XO  = OFF_XVT + (size_t)512 * 1024;
static constexpr size_t OFF_P   = OFF_XO + (size_t)2 * 1024 * 1024;

// ---------------------------------------------------------------------------
// fp32 -> bf16 hi/lo split (RNE). x ≈ hi + lo with residual ~2^-17 |x|.
// ---------------------------------------------------------------------------
__device__ __forceinline__ void cvt_hi_lo(float x, unsigned short& hi,
                                          unsigned short& lo) {
  unsigned u = __float_as_uint(x);
  unsigned rh = (u + 0x7FFFu + ((u >> 16) & 1u)) & 0xFFFF0000u;
  hi = (unsigned short)(rh >> 16);
  float xl = x - __uint_as_float(rh);
  unsigned ul = __float_as_uint(xl);
  unsigned rl = ul + 0x7FFFu + ((ul >> 16) & 1u);
  lo = (unsigned short)(rl >> 16);
}

// ---------------------------------------------------------------------------
// Unified NT GEMM core, MFMA bf16x3 (R5-proven, do not touch).
// ---------------------------------------------------------------------------
template <int EPI>
__device__ __forceinline__ void mfma_nt_core(
    const float* __restrict__ A, int lda,
    const float* __restrict__ B, int ldb,
    float* __restrict__ C, int ldc, int K,
    const float* __restrict__ bias)
{
  __shared__ __align__(16) unsigned short Ah[64][40];
  __shared__ __align__(16) unsigned short Al[64][40];
  __shared__ __align__(16) unsigned short Bh[64][40];
  __shared__ __align__(16) unsigned short Bl[64][40];

  const int bm = blockIdx.y << 6;
  const int bn = blockIdx.x << 6;
  const int tid  = threadIdx.x;
  const int lane = tid & 63;
  const int wave = tid >> 6;
  const int m16  = lane & 15;
  const int quad = lane >> 4;

  const int srow = tid >> 2;
  const int skq  = (tid & 3) << 3;

  floatx4 acc[4];
#pragma unroll
  for (int c = 0; c < 4; ++c) acc[c] = (floatx4){0.f, 0.f, 0.f, 0.f};

  for (int k0 = 0; k0 < K; k0 += 32) {
    {
      const float* ap = A + (size_t)(bm + srow) * lda + (k0 + skq);
      const float* bp = B + (size_t)(bn + srow) * ldb + (k0 + skq);
      float av[8] __attribute__((aligned(16)));
      float bv[8] __attribute__((aligned(16)));
      *(float4*)&av[0] = *(const float4*)(ap);
      *(float4*)&av[4] = *(const float4*)(ap + 4);
      *(float4*)&bv[0] = *(const float4*)(bp);
      *(float4*)&bv[4] = *(const float4*)(bp + 4);
      short8 vah, valo, vbh, vblo;
#pragma unroll
      for (int e = 0; e < 8; ++e) {
        unsigned short h, l;
        cvt_hi_lo(av[e], h, l);
        vah[e] = (short)h; valo[e] = (short)l;
        cvt_hi_lo(bv[e], h, l);
        vbh[e] = (short)h; vblo[e] = (short)l;
      }
      *(short8*)&Ah[srow][skq] = vah;
      *(short8*)&Al[srow][skq] = valo;
      *(short8*)&Bh[srow][skq] = vbh;
      *(short8*)&Bl[srow][skq] = vblo;
    }
    __syncthreads();

    const int arow = (wave << 4) + m16;
    const short8 a_h = *(const short8*)&Ah[arow][quad << 3];
    const short8 a_l = *(const short8*)&Al[arow][quad << 3];
#pragma unroll
    for (int c = 0; c < 4; ++c) {
      const int brow = (c << 4) + m16;
      const short8 b_h = *(const short8*)&Bh[brow][quad << 3];
      const short8 b_l = *(const short8*)&Bl[brow][quad << 3];
      acc[c] = __builtin_amdgcn_mfma_f32_16x16x32_bf16(a_h, b_h, acc[c], 0, 0, 0);
      acc[c] = __builtin_amdgcn_mfma_f32_16x16x32_bf16(a_h, b_l, acc[c], 0, 0, 0);
      acc[c] = __builtin_amdgcn_mfma_f32_16x16x32_bf16(a_l, b_h, acc[c], 0, 0, 0);
    }
    __syncthreads();
  }

#pragma unroll
  for (int c = 0; c < 4; ++c) {
#pragma unroll
    for (int r = 0; r < 4; ++r) {
      const int row = (wave << 4) + (quad << 2) + r;
      const int col = (c << 4) + m16;
      float v = acc[c][r];
      if (EPI == 0) { if (bias) v += bias[bn + col]; }
      if (EPI == 1) { v += bias[bm + row]; }
      if (EPI == 2) {
        v = 1.0f / (1.0f + expf(-v));
        v = fminf(fmaxf(v, 0.001f), 0.999f);
      }
      C[(size_t)(bm + row) * ldc + (bn + col)] = v;
    }
  }
}

__global__ __launch_bounds__(256) void gemm_nt_mfma_k(
    const float* __restrict__ A, int lda, const float* __restrict__ W, int ldw,
    const float* __restrict__ bias, float* __restrict__ C, int ldc, int K)
{
  mfma_nt_core<0>(A, lda, W, ldw, C, ldc, K, bias);
}

__global__ __launch_bounds__(256) void proj_vt_k(
    const float* __restrict__ vw, const float* __restrict__ value,
    const float* __restrict__ vb, float* __restrict__ XVt)
{
  const int b = blockIdx.z;
  mfma_nt_core<1>(vw, 1024, value + ((size_t)b << 20), 1024,
                  XVt + (size_t)b * 256 * 1024, 1024, 1024, vb);
}

__global__ __launch_bounds__(256) void scores_mfma_k(
    const float* __restrict__ XQ, const float* __restrict__ XK,
    float* __restrict__ P)
{
  const int z = blockIdx.z;
  const int b = z >> 4;
  mfma_nt_core<2>(XQ + ((size_t)b << 20) + ((size_t)(z & 15) << 6), 1024,
                  XK + (size_t)b * TSEQ * 256 + ((size_t)(z & 3) << 6), 256,
                  P + ((size_t)z << 20), 1024, 64, nullptr);
}

__global__ __launch_bounds__(256) void pv_mfma_k(
    const float* __restrict__ P, const float* __restrict__ XVt,
    float* __restrict__ XO)
{
  const int z = blockIdx.z;
  const int b = z >> 4;
  mfma_nt_core<0>(P + ((size_t)z << 20), 1024,
                  XVt + (size_t)b * 256 * 1024 + (size_t)(z & 3) * 64 * 1024, 1024,
                  XO + ((size_t)b << 20) + ((size_t)(z & 15) << 6), 1024,
                  1024, nullptr);
}

// ---------------------------------------------------------------------------
// Monotonic recurrence, in place over P (probs -> phi). ONE WAVE per z.
// R7-proven 2-row pair-scan structure, with the wave scan upgraded from
// radix-2 (6 dependent shuffle rounds) to RADIX-4 (3 rounds: steps 1,4,16;
// 3 neighbor tuples per stage, 15 shuffles issued together = one latency).
// Compose op = R7's proven 5-tuple combine, applied k=1,2,3 sequentially
// with pre-stage fetches and t>=k*step guards (standard KS generalization:
// segments [t-4s+1..t] after each stage). Everything else verbatim R7.
// ---------------------------------------------------------------------------
__global__ __launch_bounds__(64) void mono_rec_k(float* __restrict__ P)
{
  const int z = blockIdx.x;
  float* __restrict__ Pz = P + ((size_t)z << 20);
  const int t = threadIdx.x;
  const int col0 = t << 4;
  const int bofs = (t == 0) ? 0 : (col0 - 1);

  float b[16];

  const float p00 = Pz[0];
  {
    float4 z4 = make_float4(0.f, 0.f, 0.f, 0.f);
    float4 v0 = z4;
    if (t == 0) v0.x = 1.0f;
    *(float4*)(Pz + col0 + 0)  = v0;
    *(float4*)(Pz + col0 + 4)  = z4;
    *(float4*)(Pz + col0 + 8)  = z4;
    *(float4*)(Pz + col0 + 12) = z4;
  }
#pragma unroll
  for (int c = 0; c < 16; ++c) b[c] = 0.0f;
  if (t == 0) b[0] = p00;

  {
    float pu1[16];
#pragma unroll
    for (int q = 0; q < 4; ++q)
      *(float4*)&pu1[4 * q] = *(const float4*)(Pz + ((size_t)1 << 10) + col0 + 4 * q);

    const float pl = __shfl_up(pu1[15], 1);
    const float A0 = (t == 0) ? 0.0f : (1.0f - pl);
    float SA[16], SB[16];
    SA[0] = A0;
    SB[0] = b[0];
#pragma unroll
    for (int c = 1; c < 16; ++c) {
      const float Ac = 1.0f - pu1[c - 1];
      SA[c] = SA[c - 1] * Ac;
      SB[c] = fmaf(SB[c - 1], Ac, b[c]);
    }
    float tA = SA[15], tB = SB[15];
#pragma unroll
    for (int off = 1; off < 64; off <<= 1) {
      const float uA = __shfl_up(tA, off);
      const float uB = __shfl_up(tB, off);
      if (t >= off) { tB = fmaf(uB, tA, tB); tA = uA * tA; }
    }
    float pB = __shfl_up(tB, 1);
    if (t == 0) pB = 0.0f;
    float phin[16];
#pragma unroll
    for (int c = 0; c < 16; ++c) {
      phin[c] = fmaf(pB, SA[c], SB[c]);
      b[c] = phin[c] * pu1[c];
    }
    float* rowp = Pz + ((size_t)1 << 10) + col0;
#pragma unroll
    for (int q = 0; q < 4; ++q)
      *(float4*)(rowp + 4 * q) = *(float4*)&phin[4 * q];
  }

  float cu[16], cv[16], wu[16], wv[16];
  float cqu, cqv, wqu, wqv;

#pragma unroll
  for (int q = 0; q < 4; ++q) {
    *(float4*)&cu[4 * q] = *(const float4*)(Pz + ((size_t)2 << 10) + col0 + 4 * q);
    *(float4*)&cv[4 * q] = *(const float4*)(Pz + ((size_t)3 << 10) + col0 + 4 * q);
  }
  cqu = Pz[((size_t)2 << 10) + bofs];
  cqv = Pz[((size_t)3 << 10) + bofs];

  auto pass2 = [&](int i, float (&up)[16], float (&vp)[16],
                   const float qu, const float qv,
                   float (&pwu)[16], float (&pwv)[16],
                   float& pqu, float& pqv) {
    const size_t r2 = (size_t)((i + 2 < TSEQ) ? (i + 2) : (TSEQ - 1)) << 10;
    const size_t r3 = (size_t)((i + 3 < TSEQ) ? (i + 3) : (TSEQ - 1)) << 10;
#pragma unroll
    for (int q = 0; q < 4; ++q) {
      *(float4*)&pwu[4 * q] = *(const float4*)(Pz + r2 + col0 + 4 * q);
      *(float4*)&pwv[4 * q] = *(const float4*)(Pz + r3 + col0 + 4 * q);
    }
    pqu = Pz[r2 + bofs];
    pqv = Pz[r3 + bofs];

    const float H0 = (t == 0) ? 0.0f : (1.0f - qu);
    const float G0 = (t == 0) ? 0.0f : (1.0f - qv);

    float a = H0, d = G0;
    float bx = b[0];
    float cc = up[0] * a;
    float by = up[0] * bx;
#pragma unroll
    for (int c = 1; c < 16; ++c) {
      const float H  = 1.0f - up[c - 1];
      const float G  = 1.0f - vp[c - 1];
      const float qq = up[c];
      a  = H * a;
      bx = fmaf(H, bx, b[c]);
      cc = fmaf(G, cc, qq * a);
      by = fmaf(G, by, qq * bx);
      d  = G * d;
    }

    // --- RADIX-4 Kogge-Stone over lane maps (3 rounds instead of 6) ---
    auto stage = [&](const int step) {
      float ua[3], ucc[3], ud[3], ubx[3], uby[3];
#pragma unroll
      for (int k = 0; k < 3; ++k) {
        const int off = step * (k + 1);
        ua[k]  = __shfl_up(a,  off);
        ucc[k] = __shfl_up(cc, off);
        ud[k]  = __shfl_up(d,  off);
        ubx[k] = __shfl_up(bx, off);
        uby[k] = __shfl_up(by, off);
      }
#pragma unroll
      for (int k = 0; k < 3; ++k) {
        if (t >= step * (k + 1)) {
          const float nbx = fmaf(a, ubx[k], bx);
          const float nby = fmaf(cc, ubx[k], fmaf(d, uby[k], by));
          const float ncc = fmaf(cc, ua[k], d * ucc[k]);
          a = a * ua[k];
          d = d * ud[k];
          bx = nbx; by = nby; cc = ncc;
        }
      }
    };
    stage(1);
    stage(4);
    stage(16);

    float Xx = __shfl_up(bx, 1);
    float Xy = __shfl_up(by, 1);
    if (t == 0) { Xx = 0.0f; Xy = 0.0f; }

    float xa[16], ya[16];
    float x = fmaf(H0, Xx, b[0]);
    float y = fmaf(G0, Xy, up[0] * x);
    xa[0] = x; ya[0] = y; b[0] = y * vp[0];
#pragma unroll
    for (int c = 1; c < 16; ++c) {
      x = fmaf(1.0f - up[c - 1], x, b[c]);
      y = fmaf(1.0f - vp[c - 1], y, up[c] * x);
      xa[c] = x; ya[c] = y; b[c] = y * vp[c];
    }
    float* rowu = Pz + ((size_t)i << 10) + col0;
    float* rowv = rowu + TSEQ;
#pragma unroll
    for (int q = 0; q < 4; ++q) {
      *(float4*)(rowu + 4 * q) = *(float4*)&xa[4 * q];
      *(float4*)(rowv + 4 * q) = *(float4*)&ya[4 * q];
    }
  };

  int i = 2;
  for (int k = 0; k < 255; ++k) {
    pass2(i, cu, cv, cqu, cqv, wu, wv, wqu, wqv);
    pass2(i + 2, wu, wv, wqu, wqv, cu, cv, cqu, cqv);
    i += 4;
  }
  pass2(1022, cu, cv, cqu, cqv, wu, wv, wqu, wqv);
}

// ---------------------------------------------------------------------------
extern "C" void kernel_launch(void* const* d_in, const int* in_sizes, int n_in,
                              void* d_out, int out_size, void* d_ws, size_t ws_size,
                              hipStream_t stream)
{
  const float* query = (const float*)d_in[0];
  const float* key   = (const float*)d_in[1];
  const float* value = (const float*)d_in[2];
  const float* ipw   = (const float*)d_in[3];   // (1536,1024)
  const float* ipb   = (const float*)d_in[4];   // (1536,)
  const float* opw   = (const float*)d_in[5];   // (1024,1024)
  const float* opb   = (const float*)d_in[6];   // (1024,)
  float* out = (float*)d_out;
  float* ws  = (float*)d_ws;

  float* XQ  = ws + OFF_XQ;
  float* XK  = ws + OFF_XK;
  float* XVt = ws + OFF_XVT;
  float* XO  = ws + OFF_XO;
  float* P   = ws + OFF_P;

  // in-projections (MFMA bf16x3)
  gemm_nt_mfma_k<<<dim3(16, 32), 256, 0, stream>>>(
      query, 1024, ipw, 1024, ipb, XQ, 1024, 1024);
  gemm_nt_mfma_k<<<dim3(4, 32), 256, 0, stream>>>(
      key, 1024, ipw + (size_t)1024 * 1024, 1024, ipb + 1024, XK, 256, 1024);
  proj_vt_k<<<dim3(16, 4, 2), 256, 0, stream>>>(
      ipw + (size_t)1280 * 1024, value, ipb + 1280, XVt);

  // scores + sigmoid + clip -> P
  scores_mfma_k<<<dim3(16, 16, 32), 256, 0, stream>>>(XQ, XK, P);

  // monotonic recurrence in place (pair-scan, radix-4 wave scan)
  mono_rec_k<<<dim3(32), dim3(64), 0, stream>>>(P);

  // phi @ V -> XO (NT against transposed V)
  pv_mfma_k<<<dim3(1, 16, 32), 256, 0, stream>>>(P, XVt, XO);

  // out-projection
  gemm_nt_mfma_k<<<dim3(16, 32), 256, 0, stream>>>(
      XO, 1024, opw, 1024, opb, out, 1024, 1024);
}